// Round 1
// baseline (4840.377 us; speedup 1.0000x reference)
//
#include <hip/hip_runtime.h>
#include <math.h>

namespace {
constexpr float kDT  = 0.01f;   // DT / SUBSTEP, SUBSTEP == 1
constexpr int   kIter = 10;
constexpr float kH   = -2.0f;
constexpr float kEps = 1e-5f;
constexpr int   kB = 8;
constexpr int   kN = 50000;
constexpr int   kE = 200000;
}

// Vp = V + dt * (vel + dt*F/m)
__global__ void predict_kernel(const float* __restrict__ V,
                               const float* __restrict__ Vvel,
                               const float* __restrict__ Vmass,
                               const float* __restrict__ Vforce,
                               float* __restrict__ Vp) {
    int idx = blockIdx.x * blockDim.x + threadIdx.x;
    if (idx >= kB * kN) return;
    float m = Vmass[idx];
#pragma unroll
    for (int c = 0; c < 3; ++c) {
        int k = idx * 3 + c;
        float vel_pred = Vvel[k] + (kDT * Vforce[k]) / m;  // (dt*F)/m, reference order
        Vp[k] = V[k] + kDT * vel_pred;
    }
}

// One Jacobi sweep: read VpOld (frozen), scatter-add into VpNew (pre-copied from VpOld).
__global__ void constraint_kernel(const float* __restrict__ VpOld,
                                  float* __restrict__ VpNew,
                                  float* __restrict__ L,
                                  const float* __restrict__ Vw,
                                  const float* __restrict__ Vcomp,
                                  const float* __restrict__ Cinit,
                                  const int* __restrict__ Cdist) {
    int idx = blockIdx.x * blockDim.x + threadIdx.x;  // b*E + e  (e fast -> coalesced Cdist/L)
    if (idx >= kB * kE) return;
    int e = idx % kE;
    int b = idx / kE;
    int vi = Cdist[2 * e + 0];
    int vj = Cdist[2 * e + 1];
    size_t base = (size_t)b * kN;

    const float* pi = VpOld + (base + vi) * 3;
    const float* pj = VpOld + (base + vj) * 3;
    float nx = pi[0] - pj[0];
    float ny = pi[1] - pj[1];
    float nz = pi[2] - pj[2];
    float D = sqrtf(nx * nx + ny * ny + nz * nz);
    float C = D - Cinit[e];

    float wi = Vw[base + vi];
    float wj = Vw[base + vj];
    float A = (Vcomp[base + vi] + Vcomp[base + vj]) * 0.5f;
    float S = wi + wj;
    if (S == 0.0f) S = INFINITY;

    float Lold = L[idx];
    float Ld = (-C - A * Lold) / (S + A);
    L[idx] = Lold + Ld;

    float ux = Ld * (nx / D);   // Nvec / D per component, reference order
    float uy = Ld * (ny / D);
    float uz = Ld * (nz / D);

    float* qi = VpNew + (base + vi) * 3;
    float* qj = VpNew + (base + vj) * 3;
    atomicAdd(&qi[0], wi * ux);
    atomicAdd(&qi[1], wi * uy);
    atomicAdd(&qi[2], wi * uz);
    atomicAdd(&qj[0], -(wj * ux));
    atomicAdd(&qj[1], -(wj * uy));
    atomicAdd(&qj[2], -(wj * uz));
}

// Plane collision + velocity write-back.
__global__ void finalize_kernel(const float* __restrict__ V,
                                const float* __restrict__ Vp,
                                float* __restrict__ outV,
                                float* __restrict__ outVel) {
    int idx = blockIdx.x * blockDim.x + threadIdx.x;
    if (idx >= kB * kN) return;
    int k = idx * 3;
    float vx = V[k], vy = V[k + 1], vz0 = V[k + 2];
    float px = Vp[k], py = Vp[k + 1], pz = Vp[k + 2];

    bool col = (pz < kH) && (vz0 > kH);
    float h_prev = vz0 - kH;
    float h_after = kH - pz;
    float denom = col ? (h_prev + h_after) : 1.0f;
    float t = h_prev / denom;

    float x  = col ? (vx + t * (px - vx)) : px;
    float y  = col ? (vy + t * (py - vy)) : py;
    float z1 = col ? (kH + kEps) : pz;

    bool vio = (z1 < kH) && (vz0 < kH);
    float z2 = vio ? (kH + kEps) : z1;

    float velx = (x  - vx ) / kDT;
    float vely = (y  - vy ) / kDT;
    float velz = (z2 - vz0) / kDT;
    velz = col ? -velz : velz;
    velz = vio ? 0.0f : velz;

    outV[k] = x;  outV[k + 1] = y;  outV[k + 2] = z2;
    outVel[k] = velx; outVel[k + 1] = vely; outVel[k + 2] = velz;
}

extern "C" void kernel_launch(void* const* d_in, const int* in_sizes, int n_in,
                              void* d_out, int out_size, void* d_ws, size_t ws_size,
                              hipStream_t stream) {
    const float* V      = (const float*)d_in[0];
    const float* Vvel   = (const float*)d_in[1];
    const float* Vw     = (const float*)d_in[2];
    const float* Vcomp  = (const float*)d_in[3];
    const float* Vmass  = (const float*)d_in[4];
    const float* Vforce = (const float*)d_in[5];
    const float* Cinit  = (const float*)d_in[6];
    const int*   Cdist  = (const int*)d_in[7];

    float* VpA = (float*)d_ws;
    float* VpB = VpA + (size_t)kB * kN * 3;
    float* L   = VpB + (size_t)kB * kN * 3;
    size_t vpBytes = (size_t)kB * kN * 3 * sizeof(float);

    hipMemsetAsync(L, 0, (size_t)kB * kE * sizeof(float), stream);

    const int bn = kB * kN;
    const int be = kB * kE;
    dim3 blk(256);

    predict_kernel<<<dim3((bn + 255) / 256), blk, 0, stream>>>(V, Vvel, Vmass, Vforce, VpA);

    for (int it = 0; it < kIter; ++it) {
        float* src = (it & 1) ? VpB : VpA;
        float* dst = (it & 1) ? VpA : VpB;
        hipMemcpyAsync(dst, src, vpBytes, hipMemcpyDeviceToDevice, stream);
        constraint_kernel<<<dim3((be + 255) / 256), blk, 0, stream>>>(src, dst, L,
                                                                      Vw, Vcomp, Cinit, Cdist);
    }
    // After an even number of sweeps the result is back in VpA.
    float* outV   = (float*)d_out;
    float* outVel = outV + (size_t)kB * kN * 3;
    finalize_kernel<<<dim3((bn + 255) / 256), blk, 0, stream>>>(V, VpA, outV, outVel);
}

// Round 2
// 669.493 us; speedup vs baseline: 7.2299x; 7.2299x over previous
//
#include <hip/hip_runtime.h>
#include <math.h>

namespace {
constexpr float kDT  = 0.01f;   // DT / SUBSTEP, SUBSTEP == 1
constexpr int   kIter = 10;
constexpr float kH   = -2.0f;
constexpr float kEps = 1e-5f;
constexpr int   kB = 8;
constexpr int   kN = 50000;
constexpr int   kE = 200000;
constexpr int   kBN = kB * kN;
constexpr int   kBE = kB * kE;
}

// ---------------- CSR build (once per launch) ----------------

__global__ void count_kernel(const int* __restrict__ Cdist, int* __restrict__ counts) {
    int e = blockIdx.x * blockDim.x + threadIdx.x;
    if (e >= kE) return;
    atomicAdd(&counts[Cdist[2 * e + 0]], 1);
    atomicAdd(&counts[Cdist[2 * e + 1]], 1);
}

// Exclusive scan of counts[0..N) -> start[0..N]; single block of 1024 threads.
__global__ void scan_kernel(const int* __restrict__ counts, int* __restrict__ start) {
    __shared__ int csum[1024];
    const int tid = threadIdx.x;
    const int CH = (kN + 1023) / 1024;       // 49
    int lo = tid * CH;
    int hi = lo + CH; if (hi > kN) hi = kN;
    int s = 0;
    for (int v = lo; v < hi; ++v) s += counts[v];
    csum[tid] = s;
    __syncthreads();
    for (int off = 1; off < 1024; off <<= 1) {
        int val = 0;
        if (tid >= off) val = csum[tid - off];
        __syncthreads();
        if (tid >= off) csum[tid] += val;
        __syncthreads();
    }
    int base = (tid == 0) ? 0 : csum[tid - 1];
    for (int v = lo; v < hi; ++v) { start[v] = base; base += counts[v]; }
    if (tid == 0) start[kN] = 2 * kE;
}

// inc id = 2*e + side (side 0: i endpoint, +; side 1: j endpoint, -)
__global__ void fill_kernel(const int* __restrict__ Cdist, int* __restrict__ cursor,
                            int* __restrict__ inc) {
    int e = blockIdx.x * blockDim.x + threadIdx.x;
    if (e >= kE) return;
    int vi = Cdist[2 * e + 0];
    int vj = Cdist[2 * e + 1];
    int p0 = atomicAdd(&cursor[vi], 1);
    inc[p0] = 2 * e;
    int p1 = atomicAdd(&cursor[vj], 1);
    inc[p1] = 2 * e + 1;
}

// Deterministic order regardless of fill scheduling: sort each segment.
__global__ void sort_kernel(const int* __restrict__ start, int* __restrict__ inc) {
    int v = blockIdx.x * blockDim.x + threadIdx.x;
    if (v >= kN) return;
    int s0 = start[v], s1 = start[v + 1];
    for (int a = s0 + 1; a < s1; ++a) {
        int key = inc[a];
        int b = a - 1;
        while (b >= s0 && inc[b] > key) { inc[b + 1] = inc[b]; --b; }
        inc[b + 1] = key;
    }
}

// ---------------- physics ----------------

// Per (b,e): A = (comp_i+comp_j)/2, SA = S + A with S==0 -> inf. Constant over sweeps.
__global__ void precompute_kernel(const int* __restrict__ Cdist,
                                  const float* __restrict__ Vw,
                                  const float* __restrict__ Vcomp,
                                  float2* __restrict__ AS) {
    int b = blockIdx.x & 7;
    int e = (blockIdx.x >> 3) * blockDim.x + threadIdx.x;
    if (e >= kE) return;
    int vi = Cdist[2 * e + 0];
    int vj = Cdist[2 * e + 1];
    size_t base = (size_t)b * kN;
    float A = (Vcomp[base + vi] + Vcomp[base + vj]) * 0.5f;
    float S = Vw[base + vi] + Vw[base + vj];
    if (S == 0.0f) S = INFINITY;
    AS[(size_t)b * kE + e] = make_float2(A, S + A);
}

__global__ void predict_kernel(const float* __restrict__ V,
                               const float* __restrict__ Vvel,
                               const float* __restrict__ Vmass,
                               const float* __restrict__ Vforce,
                               float* __restrict__ Vp) {
    int idx = blockIdx.x * blockDim.x + threadIdx.x;
    if (idx >= kBN) return;
    float m = Vmass[idx];
#pragma unroll
    for (int c = 0; c < 3; ++c) {
        int k = idx * 3 + c;
        float vel_pred = Vvel[k] + (kDT * Vforce[k]) / m;  // (dt*F)/m, reference order
        Vp[k] = V[k] + kDT * vel_pred;
    }
}

// Phase 1 of a Jacobi sweep: per-constraint correction, no scatter.
__global__ void solve_kernel(const float* __restrict__ Vp,
                             float* __restrict__ L,
                             const float2* __restrict__ AS,
                             const float* __restrict__ Cinit,
                             const int* __restrict__ Cdist,
                             float* __restrict__ upd) {
    int b = blockIdx.x & 7;                      // batch -> XCD locality
    int e = (blockIdx.x >> 3) * blockDim.x + threadIdx.x;
    if (e >= kE) return;
    int vi = Cdist[2 * e + 0];
    int vj = Cdist[2 * e + 1];
    size_t vbase = (size_t)b * kN;

    const float* pi = Vp + (vbase + vi) * 3;
    const float* pj = Vp + (vbase + vj) * 3;
    float nx = pi[0] - pj[0];
    float ny = pi[1] - pj[1];
    float nz = pi[2] - pj[2];
    float D = sqrtf(nx * nx + ny * ny + nz * nz);
    float C = D - Cinit[e];

    size_t ebase = (size_t)b * kE + e;
    float2 as = AS[ebase];
    float Lold = L[ebase];
    float Ld = (-C - as.x * Lold) / as.y;
    L[ebase] = Lold + Ld;

    float* u = upd + ebase * 3;
    u[0] = Ld * (nx / D);    // Nvec / D per component, reference order
    u[1] = Ld * (ny / D);
    u[2] = Ld * (nz / D);
}

// Phase 2: per-vertex gather of incident corrections (deterministic order).
__global__ void apply_kernel(const float* __restrict__ VpSrc,
                             float* __restrict__ VpDst,
                             const float* __restrict__ upd,
                             const float* __restrict__ Vw,
                             const int* __restrict__ start,
                             const int* __restrict__ inc) {
    int b = blockIdx.x & 7;
    int v = (blockIdx.x >> 3) * blockDim.x + threadIdx.x;
    if (v >= kN) return;
    int s0 = start[v], s1 = start[v + 1];
    float sx = 0.f, sy = 0.f, sz = 0.f;
    size_t ubase = (size_t)b * kE;
    for (int k = s0; k < s1; ++k) {
        int ic = inc[k];
        const float* u = upd + (ubase + (ic >> 1)) * 3;
        if (ic & 1) { sx -= u[0]; sy -= u[1]; sz -= u[2]; }
        else        { sx += u[0]; sy += u[1]; sz += u[2]; }
    }
    size_t idx = (size_t)b * kN + v;
    float w = Vw[idx];
    const float* ps = VpSrc + idx * 3;
    float* pd = VpDst + idx * 3;
    pd[0] = ps[0] + w * sx;
    pd[1] = ps[1] + w * sy;
    pd[2] = ps[2] + w * sz;
}

__global__ void finalize_kernel(const float* __restrict__ V,
                                const float* __restrict__ Vp,
                                float* __restrict__ outV,
                                float* __restrict__ outVel) {
    int idx = blockIdx.x * blockDim.x + threadIdx.x;
    if (idx >= kBN) return;
    int k = idx * 3;
    float vx = V[k], vy = V[k + 1], vz0 = V[k + 2];
    float px = Vp[k], py = Vp[k + 1], pz = Vp[k + 2];

    bool col = (pz < kH) && (vz0 > kH);
    float h_prev = vz0 - kH;
    float h_after = kH - pz;
    float denom = col ? (h_prev + h_after) : 1.0f;
    float t = h_prev / denom;

    float x  = col ? (vx + t * (px - vx)) : px;
    float y  = col ? (vy + t * (py - vy)) : py;
    float z1 = col ? (kH + kEps) : pz;

    bool vio = (z1 < kH) && (vz0 < kH);
    float z2 = vio ? (kH + kEps) : z1;

    float velx = (x  - vx ) / kDT;
    float vely = (y  - vy ) / kDT;
    float velz = (z2 - vz0) / kDT;
    velz = col ? -velz : velz;
    velz = vio ? 0.0f : velz;

    outV[k] = x;  outV[k + 1] = y;  outV[k + 2] = z2;
    outVel[k] = velx; outVel[k + 1] = vely; outVel[k + 2] = velz;
}

// ---------------- launch ----------------

extern "C" void kernel_launch(void* const* d_in, const int* in_sizes, int n_in,
                              void* d_out, int out_size, void* d_ws, size_t ws_size,
                              hipStream_t stream) {
    const float* V      = (const float*)d_in[0];
    const float* Vvel   = (const float*)d_in[1];
    const float* Vw     = (const float*)d_in[2];
    const float* Vcomp  = (const float*)d_in[3];
    const float* Vmass  = (const float*)d_in[4];
    const float* Vforce = (const float*)d_in[5];
    const float* Cinit  = (const float*)d_in[6];
    const int*   Cdist  = (const int*)d_in[7];

    float* f = (float*)d_ws;
    float*  VpA   = f;                       // 1.2M
    float*  VpB   = VpA + (size_t)kBN * 3;   // 1.2M
    float*  L     = VpB + (size_t)kBN * 3;   // 1.6M
    float*  upd   = L + (size_t)kBE;         // 4.8M
    float2* AS    = (float2*)(upd + (size_t)kBE * 3);   // 1.6M float2 (even float offset)
    int*    start = (int*)(AS + (size_t)kBE);           // N+1
    int*    cursor= start + (kN + 1);                   // N
    int*    inc   = cursor + kN;                        // 2E

    const int TB = 256;
    dim3 blk(TB);
    dim3 gE((kE + TB - 1) / TB);             // per-edge, single batch
    dim3 gE8(((kE + TB - 1) / TB) * 8);      // per-edge x 8 batches (b = blockIdx&7)
    dim3 gV8(((kN + TB - 1) / TB) * 8);      // per-vertex x 8 batches
    dim3 gBN((kBN + TB - 1) / TB);

    // CSR build (uses `cursor` as counts first)
    hipMemsetAsync(cursor, 0, kN * sizeof(int), stream);
    count_kernel<<<gE, blk, 0, stream>>>(Cdist, cursor);
    scan_kernel<<<1, 1024, 0, stream>>>(cursor, start);
    hipMemcpyAsync(cursor, start, kN * sizeof(int), hipMemcpyDeviceToDevice, stream);
    fill_kernel<<<gE, blk, 0, stream>>>(Cdist, cursor, inc);
    sort_kernel<<<dim3((kN + TB - 1) / TB), blk, 0, stream>>>(start, inc);

    // Invariants + prediction
    precompute_kernel<<<gE8, blk, 0, stream>>>(Cdist, Vw, Vcomp, AS);
    hipMemsetAsync(L, 0, (size_t)kBE * sizeof(float), stream);
    predict_kernel<<<gBN, blk, 0, stream>>>(V, Vvel, Vmass, Vforce, VpA);

    for (int it = 0; it < kIter; ++it) {
        float* src = (it & 1) ? VpB : VpA;
        float* dst = (it & 1) ? VpA : VpB;
        solve_kernel<<<gE8, blk, 0, stream>>>(src, L, AS, Cinit, Cdist, upd);
        apply_kernel<<<gV8, blk, 0, stream>>>(src, dst, upd, Vw, start, inc);
    }
    // 10 sweeps: final positions are back in VpA.
    float* outV   = (float*)d_out;
    float* outVel = outV + (size_t)kBN * 3;
    finalize_kernel<<<gBN, blk, 0, stream>>>(V, VpA, outV, outVel);
}